// Round 4
// baseline (282.026 us; speedup 1.0000x reference)
//
#include <hip/hip_runtime.h>

// (B, C, H, W) = (8, 256, 64, 64); N = 4096; QK dim = 32.
#define NPIX 4096
#define CCH  256
#define CN   (CCH * NPIX)

typedef __attribute__((ext_vector_type(8)))  short short8;   // 8 bf16
typedef __attribute__((ext_vector_type(4)))  float f32x4;
typedef __attribute__((ext_vector_type(16))) float f32x16;

union U48 { uint4 u; short8 s; };

// pack two fp32 -> bf16 pair (truncation): single v_perm_b32
__device__ __forceinline__ unsigned pk2t(float lo, float hi) {
    return __builtin_amdgcn_perm(__float_as_uint(hi), __float_as_uint(lo),
                                 0x07060302u);
}
__device__ __forceinline__ unsigned short bf16t(float f) {
    return (unsigned short)(__float_as_uint(f) >> 16);
}

#define QSCALE 0.25503494f   // (1/sqrt(32)) * log2(e): scores in log2 domain

// ---------------------------------------------------------------------------
// W pre-pack: stacked [Wq(32) | Wk(32) | Wv(256)] -> bf16 rows of 256,
// Q-scale folded into Wq rows. 20480 threads, one float4 each.
// ---------------------------------------------------------------------------
__global__ __launch_bounds__(256) void wpack(
    const float* __restrict__ Wq, const float* __restrict__ Wk,
    const float* __restrict__ Wv, unsigned short* __restrict__ wb)
{
    const int idx = blockIdx.x * 256 + threadIdx.x;   // 80 blocks
    const int d = idx >> 6, c4 = (idx & 63) * 4;
    const float* src; float sc = 1.0f;
    if (d < 32)      { src = Wq + d * CCH; sc = QSCALE; }
    else if (d < 64) { src = Wk + (d - 32) * CCH; }
    else             { src = Wv + (d - 64) * CCH; }
    float4 v = *(const float4*)(src + c4);
    *(uint2*)(wb + d * CCH + c4) =
        make_uint2(pk2t(v.x * sc, v.y * sc), pk2t(v.z * sc, v.w * sc));
}

// ---------------------------------------------------------------------------
// Projections, barrier-free: out^T[n][d] = sum_c x[c][n] * W[d][c].
// One wave per block (16 n x 160 d); B-frags straight from L2-hot bf16 W;
// A-frags (x^T) via strided scalar loads + in-register pack. No LDS.
// Grid: (256 n-tiles, 2 d-halves, 8 b).
// ---------------------------------------------------------------------------
__global__ __launch_bounds__(64, 4) void proj_v4(
    const float* __restrict__ xg, const unsigned short* __restrict__ wb,
    unsigned short* __restrict__ qo, unsigned short* __restrict__ ko,
    unsigned short* __restrict__ vo)
{
    const int lane = threadIdx.x;
    const int q = lane >> 4, nlo = lane & 15;
    const int n0 = blockIdx.x * 16;
    const int dh = blockIdx.y;                 // dt range: dh*10 .. +10
    const int b  = blockIdx.z;
    const float* xb = xg + (size_t)b * CN;

    U48 A[8];                                  // x^T frags: rows n, k = c
#pragma unroll
    for (int ks = 0; ks < 8; ++ks) {
        const float* xc = xb + (size_t)(ks * 32 + q * 8) * NPIX + n0 + nlo;
        float v0 = xc[0],        v1 = xc[NPIX],     v2 = xc[2 * NPIX],
              v3 = xc[3 * NPIX], v4 = xc[4 * NPIX], v5 = xc[5 * NPIX],
              v6 = xc[6 * NPIX], v7 = xc[7 * NPIX];
        A[ks].u = make_uint4(pk2t(v0, v1), pk2t(v2, v3),
                             pk2t(v4, v5), pk2t(v6, v7));
    }

#pragma unroll
    for (int dtl = 0; dtl < 10; ++dtl) {
        const int dt = dh * 10 + dtl;
        f32x4 acc = (f32x4){0.f, 0.f, 0.f, 0.f};
#pragma unroll
        for (int ks = 0; ks < 8; ++ks) {
            U48 Bf;
            Bf.u = *(const uint4*)(wb + (size_t)(dt * 16 + nlo) * CCH
                                      + ks * 32 + q * 8);
            acc = __builtin_amdgcn_mfma_f32_16x16x32_bf16(A[ks].s, Bf.s,
                                                          acc, 0, 0, 0);
        }
        // C: col d = dt*16+nlo, rows n = n0 + q*4 + r
        const int d = dt * 16 + nlo;
        if (dt < 2) {
#pragma unroll
            for (int r = 0; r < 4; ++r)
                qo[((size_t)b * NPIX + n0 + q * 4 + r) * 32 + d] = bf16t(acc[r]);
        } else if (dt < 4) {
#pragma unroll
            for (int r = 0; r < 4; ++r)
                ko[((size_t)b * NPIX + n0 + q * 4 + r) * 32 + (d - 32)] =
                    bf16t(acc[r]);
        } else {
            const int c = d - 64;
            *(uint2*)(vo + ((size_t)b * CCH + c) * (size_t)NPIX + n0 + q * 4) =
                make_uint2(pk2t(acc[0], acc[1]), pk2t(acc[2], acc[3]));
        }
    }
}

// ---------------------------------------------------------------------------
// Flash v4: 512-thread blocks (8 waves, 4/SIMD), m-tile 128, ONE barrier/iter
// via double-buffered P.  S^T (16x16x32) m-split 8 ways; PV (32x32x16) with
// wave = (m-half sh, c-quarter cq); partial O pairs combined at the end
// through the re-aliased P buffer.  K/V/Q frags direct from global.
// ---------------------------------------------------------------------------
__global__ __launch_bounds__(512, 4) void flash_v4(
    const unsigned short* __restrict__ qg, const unsigned short* __restrict__ kg,
    const unsigned short* __restrict__ vg, const float* __restrict__ xg,
    const float* __restrict__ gp, float* __restrict__ outg)
{
    __shared__ uint4 ps4[2][64 * 16];   // P^T double-buffer: [n][m-granule], 32 KB
    __shared__ float ls[8][64];         // per-wave l partials

    const int tid = threadIdx.x, lane = tid & 63, w = tid >> 6;
    const int q = lane >> 4, nlo = lane & 15;
    const int l31 = lane & 31, l5 = lane >> 5;
    const int sh = w & 1, cq = w >> 1;  // m-half / c-quarter for PV
    const int n0 = blockIdx.x * 64, b = blockIdx.y;

    const unsigned short* qb = qg + (size_t)b * NPIX * 32;
    const unsigned short* kb = kg + (size_t)b * NPIX * 32;
    const unsigned short* vb = vg + (size_t)b * CN;

    U48 Bq[4];   // Q^T B-frags (16x16): col n = nlo, k d = q*8.., invariant
#pragma unroll
    for (int nt = 0; nt < 4; ++nt)
        Bq[nt].u = *(const uint4*)(qb + (size_t)(n0 + nt * 16 + nlo) * 32 + q * 8);

    f32x16 acc[2][2];   // [ct][nt]: c = cq*64+ct*32+row, n = nt*32+col
#pragma unroll
    for (int ct = 0; ct < 2; ++ct)
#pragma unroll
        for (int nt = 0; nt < 2; ++nt)
#pragma unroll
            for (int r = 0; r < 16; ++r) acc[ct][nt][r] = 0.f;
    float lacc[4] = {0.f, 0.f, 0.f, 0.f};

    for (int it = 0; it < 32; ++it) {
        const int m0 = it * 128;
        uint4* pbuf = ps4[it & 1];

        // ---- S phase: wave w owns m-rows [m0 + w*16, +16)
        U48 Ak;
        Ak.u = *(const uint4*)(kb + (size_t)(m0 + w * 16 + nlo) * 32 + q * 8);
        const f32x4 z = {0.f, 0.f, 0.f, 0.f};
#pragma unroll
        for (int nt = 0; nt < 4; ++nt) {
            f32x4 St = __builtin_amdgcn_mfma_f32_16x16x32_bf16(
                Ak.s, Bq[nt].s, z, 0, 0, 0);
            float p0 = __builtin_amdgcn_exp2f(St[0]);
            float p1 = __builtin_amdgcn_exp2f(St[1]);
            float p2 = __builtin_amdgcn_exp2f(St[2]);
            float p3 = __builtin_amdgcn_exp2f(St[3]);
            lacc[nt] += (p0 + p1) + (p2 + p3);
            const int n = nt * 16 + nlo;   // m-local = w*16 + q*4 + r
            ((uint2*)pbuf)[n * 32 + (((w * 2 + (q >> 1)) ^ nlo) * 2) + (q & 1)] =
                make_uint2(pk2t(p0, p1), pk2t(p2, p3));
        }
        __syncthreads();   // P visible; double-buffer makes this the only barrier

        // ---- PV phase: wave (sh, cq): m-sub = sh*64.., c = cq*64..
#pragma unroll
        for (int s = 0; s < 4; ++s) {
            U48 Bp[2], Av[2];
#pragma unroll
            for (int nt = 0; nt < 2; ++nt)
                Bp[nt].u = pbuf[(nt * 32 + l31) * 16
                                + ((sh * 8 + s * 2 + l5) ^ (lane & 15))];
#pragma unroll
            for (int ct = 0; ct < 2; ++ct)
                Av[ct].u = *(const uint4*)(
                    vb + (size_t)(cq * 64 + ct * 32 + l31) * NPIX
                       + m0 + sh * 64 + s * 16 + l5 * 8);
#pragma unroll
            for (int ct = 0; ct < 2; ++ct)
#pragma unroll
                for (int nt = 0; nt < 2; ++nt)
                    acc[ct][nt] = __builtin_amdgcn_mfma_f32_32x32x16_bf16(
                        Av[ct].s, Bp[nt].s, acc[ct][nt], 0, 0, 0);
        }
    }

    // ---- l reduction: shfl over q-rows, then across the 8 waves via LDS
#pragma unroll
    for (int nt = 0; nt < 4; ++nt) {
        float v = lacc[nt];
        v += __shfl_xor(v, 16);
        v += __shfl_xor(v, 32);
        if (q == 0) ls[w][nt * 16 + nlo] = v;
    }

    // ---- combine sh-pairs + epilogue (2 rounds over ct, P buffer re-aliased)
    float* comb = (float*)ps4;   // 4 cq x 64 lane x 2 nt x 16 = 32 KB
    const float gamma = gp[0];
    const float* xb = xg + (size_t)b * CN;
    float* ob = outg + (size_t)b * CN;

#pragma unroll
    for (int ct = 0; ct < 2; ++ct) {
        __syncthreads();   // also publishes ls on first pass; guards ps alias
        if (sh == 1) {
#pragma unroll
            for (int nt = 0; nt < 2; ++nt)
#pragma unroll
                for (int r = 0; r < 16; ++r)
                    comb[((cq * 64 + lane) * 2 + nt) * 16 + r] = acc[ct][nt][r];
        }
        __syncthreads();
        if (sh == 0) {
#pragma unroll
            for (int nt = 0; nt < 2; ++nt) {
                const int n = nt * 32 + l31;
                const float linv = 1.0f /
                    (((ls[0][n] + ls[1][n]) + (ls[2][n] + ls[3][n])) +
                     ((ls[4][n] + ls[5][n]) + (ls[6][n] + ls[7][n])));
#pragma unroll
                for (int r = 0; r < 16; ++r) {
                    float v = acc[ct][nt][r] +
                              comb[((cq * 64 + lane) * 2 + nt) * 16 + r];
                    const int c = cq * 64 + ct * 32 + (r & 3) + 8 * (r >> 2)
                                  + 4 * l5;
                    const size_t off = (size_t)c * NPIX + (n0 + n);
                    ob[off] = fmaf(gamma, v * linv, xb[off]);
                }
            }
        }
    }
}

// ---------------------------------------------------------------------------
extern "C" void kernel_launch(void* const* d_in, const int* in_sizes, int n_in,
                              void* d_out, int out_size, void* d_ws, size_t ws_size,
                              hipStream_t stream) {
    const float* x     = (const float*)d_in[0];   // (8,256,64,64)
    const float* Wq    = (const float*)d_in[1];   // (32,256)
    const float* Wk    = (const float*)d_in[2];   // (32,256)
    const float* Wv    = (const float*)d_in[3];   // (256,256)
    const float* gamma = (const float*)d_in[4];   // (1,)

    // ws: Wb bf16 160KB | Q (B,N,32) 2MB | K (B,N,32) 2MB | V (B,256,N) 16MB
    unsigned short* wb  = (unsigned short*)d_ws;
    unsigned short* qws = wb + (size_t)320 * CCH;
    unsigned short* kws = qws + (size_t)8 * NPIX * 32;
    unsigned short* vws = kws + (size_t)8 * NPIX * 32;

    wpack<<<80, 256, 0, stream>>>(Wq, Wk, Wv, wb);
    proj_v4<<<dim3(256, 2, 8), 64, 0, stream>>>(x, wb, qws, kws, vws);
    flash_v4<<<dim3(64, 8), 512, 0, stream>>>(qws, kws, vws, x, gamma,
                                              (float*)d_out);
}

// Round 5
// 260.215 us; speedup vs baseline: 1.0838x; 1.0838x over previous
//
#include <hip/hip_runtime.h>

// (B, C, H, W) = (8, 256, 64, 64); N = 4096; QK dim = 32.
#define NPIX 4096
#define CCH  256
#define CN   (CCH * NPIX)

typedef __attribute__((ext_vector_type(8)))  short short8;   // 8 bf16
typedef __attribute__((ext_vector_type(4)))  float f32x4;
typedef __attribute__((ext_vector_type(16))) float f32x16;

union U48 { uint4 u; short8 s; };

// pack two fp32 -> bf16 pair (truncation): single v_perm_b32
__device__ __forceinline__ unsigned pk2t(float lo, float hi) {
    return __builtin_amdgcn_perm(__float_as_uint(hi), __float_as_uint(lo),
                                 0x07060302u);
}
__device__ __forceinline__ unsigned short bf16t(float f) {
    return (unsigned short)(__float_as_uint(f) >> 16);
}

#define QSCALE 0.25503494f   // (1/sqrt(32)) * log2(e): scores in log2 domain

// ---------------------------------------------------------------------------
// W pre-pack: stacked [Wq(32) | Wk(32) | Wv(256)] -> bf16 rows of 256,
// Q-scale folded into Wq rows.
// ---------------------------------------------------------------------------
__global__ __launch_bounds__(256) void wpack(
    const float* __restrict__ Wq, const float* __restrict__ Wk,
    const float* __restrict__ Wv, unsigned short* __restrict__ wb)
{
    const int idx = blockIdx.x * 256 + threadIdx.x;   // 80 blocks
    const int d = idx >> 6, c4 = (idx & 63) * 4;
    const float* src; float sc = 1.0f;
    if (d < 32)      { src = Wq + d * CCH; sc = QSCALE; }
    else if (d < 64) { src = Wk + (d - 32) * CCH; }
    else             { src = Wv + (d - 64) * CCH; }
    float4 v = *(const float4*)(src + c4);
    *(uint2*)(wb + d * CCH + c4) =
        make_uint2(pk2t(v.x * sc, v.y * sc), pk2t(v.z * sc, v.w * sc));
}

// ---------------------------------------------------------------------------
// Projections, barrier-free: out^T[n][d] = sum_c x[c][n] * W[d][c].
// 256-thread blocks; wave w owns n-subtile n0 + w*16 (block covers 64 n,
// so the 4 waves' A-loads together span full 256 B lines per x row).
// B-frags straight from L2-hot bf16 W. Grid: (64 n-tiles, 2 d-halves, 8 b).
// ---------------------------------------------------------------------------
__global__ __launch_bounds__(256, 4) void proj_v5(
    const float* __restrict__ xg, const unsigned short* __restrict__ wb,
    unsigned short* __restrict__ qo, unsigned short* __restrict__ ko,
    unsigned short* __restrict__ vo)
{
    const int tid = threadIdx.x, lane = tid & 63, w = tid >> 6;
    const int q = lane >> 4, nlo = lane & 15;
    const int n0 = blockIdx.x * 64 + w * 16;
    const int dh = blockIdx.y;                 // dt range: dh*10 .. +10
    const int b  = blockIdx.z;
    const float* xb = xg + (size_t)b * CN;

    U48 A[8];                                  // x^T frags: rows n, k = c
#pragma unroll
    for (int ks = 0; ks < 8; ++ks) {
        const float* xc = xb + (size_t)(ks * 32 + q * 8) * NPIX + n0 + nlo;
        float v0 = xc[0],        v1 = xc[NPIX],     v2 = xc[2 * NPIX],
              v3 = xc[3 * NPIX], v4 = xc[4 * NPIX], v5 = xc[5 * NPIX],
              v6 = xc[6 * NPIX], v7 = xc[7 * NPIX];
        A[ks].u = make_uint4(pk2t(v0, v1), pk2t(v2, v3),
                             pk2t(v4, v5), pk2t(v6, v7));
    }

#pragma unroll
    for (int dtl = 0; dtl < 10; ++dtl) {
        const int dt = dh * 10 + dtl;
        f32x4 acc = (f32x4){0.f, 0.f, 0.f, 0.f};
#pragma unroll
        for (int ks = 0; ks < 8; ++ks) {
            U48 Bf;
            Bf.u = *(const uint4*)(wb + (size_t)(dt * 16 + nlo) * CCH
                                      + ks * 32 + q * 8);
            acc = __builtin_amdgcn_mfma_f32_16x16x32_bf16(A[ks].s, Bf.s,
                                                          acc, 0, 0, 0);
        }
        // C: col d = dt*16+nlo, rows n = n0 + q*4 + r
        const int d = dt * 16 + nlo;
        if (dt < 2) {
#pragma unroll
            for (int r = 0; r < 4; ++r)
                qo[((size_t)b * NPIX + n0 + q * 4 + r) * 32 + d] = bf16t(acc[r]);
        } else if (dt < 4) {
#pragma unroll
            for (int r = 0; r < 4; ++r)
                ko[((size_t)b * NPIX + n0 + q * 4 + r) * 32 + (d - 32)] =
                    bf16t(acc[r]);
        } else {
            const int c = d - 64;
            *(uint2*)(vo + ((size_t)b * CCH + c) * (size_t)NPIX + n0 + q * 4) =
                make_uint2(pk2t(acc[0], acc[1]), pk2t(acc[2], acc[3]));
        }
    }
}

// ---------------------------------------------------------------------------
// Flash v5: 256-thread blocks (4 waves), block = (64-n tile, c-half, batch).
// Wave w: S-phase owns m-rows [m0+w*16,+16) (S duplicated across the two
// c-half blocks — buys register headroom); PV owns 32 channels.
// m-tile 64, ONE barrier/iter via double-buffered P; K/V frags for iter+1
// register-prefetched right after the S MFMAs consume the current K.
// acc = 32 AGPR; VGPR ~110 -> launch_bounds(256,3), 12 waves/CU, no spill.
// ---------------------------------------------------------------------------
__global__ __launch_bounds__(256, 3) void flash_v5(
    const unsigned short* __restrict__ qg, const unsigned short* __restrict__ kg,
    const unsigned short* __restrict__ vg, const float* __restrict__ xg,
    const float* __restrict__ gp, float* __restrict__ outg)
{
    __shared__ uint4 ps4[2][64 * 8];   // P dbuf: [n][8 swizzled granules], 16 KB
    __shared__ float ls[4][64];        // per-wave l partials

    const int tid = threadIdx.x, lane = tid & 63, w = tid >> 6;
    const int q = lane >> 4, nlo = lane & 15;
    const int l31 = lane & 31, l5 = lane >> 5;
    const int n0 = blockIdx.x * 64;
    const int ch = blockIdx.y;               // c-half
    const int b  = blockIdx.z;
    const int cbase = ch * 128 + w * 32;     // wave's 32 channels

    const unsigned short* qb = qg + (size_t)b * NPIX * 32;
    const unsigned short* kb = kg + (size_t)b * NPIX * 32;
    const unsigned short* vb = vg + (size_t)b * CN + (size_t)cbase * NPIX;

    U48 Bq[4];   // Q^T B-frags (16x16): col n = nlo-based, k = d; invariant
#pragma unroll
    for (int nt = 0; nt < 4; ++nt)
        Bq[nt].u = *(const uint4*)(qb + (size_t)(n0 + nt * 16 + nlo) * 32 + q * 8);

    f32x16 acc[2];   // [nt2]: c = cbase+row, n = n0 + nt2*32 + col
#pragma unroll
    for (int nt2 = 0; nt2 < 2; ++nt2)
#pragma unroll
        for (int r = 0; r < 16; ++r) acc[nt2][r] = 0.f;
    float lacc[4] = {0.f, 0.f, 0.f, 0.f};

    U48 Ak[2], Av[2][4];   // double-buffered K/V frags
    auto load_kv = [&](int m0, int bi) {
        Ak[bi].u = *(const uint4*)(kb + (size_t)(m0 + w * 16 + nlo) * 32 + q * 8);
#pragma unroll
        for (int ks2 = 0; ks2 < 4; ++ks2)
            Av[bi][ks2].u = *(const uint4*)(
                vb + (size_t)l31 * NPIX + m0 + ks2 * 16 + l5 * 8);
    };

    auto body = [&](int it, int bi) {
        const int m0 = it * 64;
        uint4* pb = ps4[it & 1];

        // ---- S: wave w owns m-rows [m0+w*16,+16): 4 MFMAs (16x16x32)
        f32x4 St[4];
        const f32x4 z = {0.f, 0.f, 0.f, 0.f};
#pragma unroll
        for (int nt = 0; nt < 4; ++nt)
            St[nt] = __builtin_amdgcn_mfma_f32_16x16x32_bf16(
                Ak[bi].s, Bq[nt].s, z, 0, 0, 0);

        if (it < 63) load_kv(m0 + 64, bi ^ 1);   // prefetch next K/V frags

        // ---- exp2 + pack + P write (granule-swizzled)
#pragma unroll
        for (int nt = 0; nt < 4; ++nt) {
            float p0 = __builtin_amdgcn_exp2f(St[nt][0]);
            float p1 = __builtin_amdgcn_exp2f(St[nt][1]);
            float p2 = __builtin_amdgcn_exp2f(St[nt][2]);
            float p3 = __builtin_amdgcn_exp2f(St[nt][3]);
            lacc[nt] += (p0 + p1) + (p2 + p3);
            const int n = nt * 16 + nlo;         // m-local = w*16 + q*4 + r
            const int g = (w * 2 + (q >> 1)) ^ (n & 7);
            ((uint2*)pb)[n * 16 + g * 2 + (q & 1)] =
                make_uint2(pk2t(p0, p1), pk2t(p2, p3));
        }
        __syncthreads();   // only barrier: P visible (dbuf guards reuse)

        // ---- PV: O += V·P, 8 MFMAs (32x32x16), V frags already in regs
#pragma unroll
        for (int ks2 = 0; ks2 < 4; ++ks2) {
            U48 Bp[2];
#pragma unroll
            for (int nt2 = 0; nt2 < 2; ++nt2)
                Bp[nt2].u = pb[(nt2 * 32 + l31) * 8
                               + ((ks2 * 2 + l5) ^ (l31 & 7))];
#pragma unroll
            for (int nt2 = 0; nt2 < 2; ++nt2)
                acc[nt2] = __builtin_amdgcn_mfma_f32_32x32x16_bf16(
                    Av[bi][ks2].s, Bp[nt2].s, acc[nt2], 0, 0, 0);
        }
    };

    load_kv(0, 0);
    for (int ii = 0; ii < 32; ++ii) {   // unroll x2: compile-time buffer index
        body(2 * ii, 0);
        body(2 * ii + 1, 1);
    }

    // ---- l reduction: shfl over q, then across the 4 waves via LDS
#pragma unroll
    for (int nt = 0; nt < 4; ++nt) {
        float v = lacc[nt];
        v += __shfl_xor(v, 16);
        v += __shfl_xor(v, 32);
        if (q == 0) ls[w][nt * 16 + nlo] = v;
    }
    __syncthreads();

    // ---- epilogue: out = gamma * (O / l) + x
    const float gamma = gp[0];
    const float* xb = xg + (size_t)b * CN;
    float* ob = outg + (size_t)b * CN;
#pragma unroll
    for (int nt2 = 0; nt2 < 2; ++nt2) {
        const int nl = nt2 * 32 + l31;
        const float linv = 1.0f /
            ((ls[0][nl] + ls[1][nl]) + (ls[2][nl] + ls[3][nl]));
        const int n = n0 + nl;
#pragma unroll
        for (int r = 0; r < 16; ++r) {
            const int c = cbase + (r & 3) + 8 * (r >> 2) + 4 * l5;
            const size_t off = (size_t)c * NPIX + n;
            ob[off] = fmaf(gamma, acc[nt2][r] * linv, xb[off]);
        }
    }
}

// ---------------------------------------------------------------------------
extern "C" void kernel_launch(void* const* d_in, const int* in_sizes, int n_in,
                              void* d_out, int out_size, void* d_ws, size_t ws_size,
                              hipStream_t stream) {
    const float* x     = (const float*)d_in[0];   // (8,256,64,64)
    const float* Wq    = (const float*)d_in[1];   // (32,256)
    const float* Wk    = (const float*)d_in[2];   // (32,256)
    const float* Wv    = (const float*)d_in[3];   // (256,256)
    const float* gamma = (const float*)d_in[4];   // (1,)

    // ws: Wb bf16 160KB | Q (B,N,32) 2MB | K (B,N,32) 2MB | V (B,256,N) 16MB
    unsigned short* wb  = (unsigned short*)d_ws;
    unsigned short* qws = wb + (size_t)320 * CCH;
    unsigned short* kws = qws + (size_t)8 * NPIX * 32;
    unsigned short* vws = kws + (size_t)8 * NPIX * 32;

    wpack<<<80, 256, 0, stream>>>(Wq, Wk, Wv, wb);
    proj_v5<<<dim3(64, 2, 8), 256, 0, stream>>>(x, wb, qws, kws, vws);
    flash_v5<<<dim3(64, 2, 8), 256, 0, stream>>>(qws, kws, vws, x, gamma,
                                                 (float*)d_out);
}